// Round 2
// baseline (342.782 us; speedup 1.0000x reference)
//
#include <hip/hip_runtime.h>

// out[(b*N + n)*D + c][s] = q[b][s][c] * w[n][c]
// B=8, S=2048, D=256, N=20, fp32 in/out.
// Measured decomposition (R0 rocprof): bench dur = harness poison-fill
// (~220 us @ 6.1 TB/s, fixed) + kernel (~120 us). Kernel moves 352 MB ->
// only ~2.9 TB/s vs the fill-demonstrated 6.1 TB/s write ceiling.
// R3 theory: write-stream concurrency too low (512 blocks = 2/CU, 8 waves).
// Fix: split N across blocks (10 classes per block) -> 1024 blocks, 4/CU,
// 16 waves/CU; nontemporal stores since output (320 MiB) is streamed once
// and exceeds the 256 MiB LLC.
// R4: nontemporal builtin needs a native vector type, not HIP float4.

namespace {
constexpr int kB = 8;
constexpr int kS = 2048;
constexpr int kD = 256;
constexpr int kN = 20;
constexpr int TS = 512;          // s-tile: 2 KB contiguous per (n,c) row
constexpr int TC = 16;           // c-tile
constexpr int NSPLIT = 2;        // n-split across blocks
constexpr int NPB = kN / NSPLIT; // 10 classes per block
constexpr int PTS = TS + 4;      // pad: row stride 516 floats breaks pow2
                                 // banking, keeps float4 LDS ops 16B-aligned

typedef float v4f __attribute__((ext_vector_type(4)));  // native vec for nt store
}

__global__ __launch_bounds__(256)
void frw_kernel(const float* __restrict__ q, const float* __restrict__ w,
                float* __restrict__ out) {
  const int s0 = blockIdx.x * TS;
  const int c0 = blockIdx.y * TC;
  const int b  = blockIdx.z >> 1;
  const int n0 = (blockIdx.z & 1) * NPB;
  const int t  = threadIdx.x;

  __shared__ float tile[TC][PTS];  // [c][s]
  __shared__ float ws[NPB][TC];

  // Preload 10x16 slice of w (160 floats).
  for (int i = t; i < NPB * TC; i += 256) {
    const int n  = i / TC;
    const int cc = i % TC;
    ws[n][cc] = w[(n0 + n) * kD + c0 + cc];
  }

  // Load 512(s) x 16(c) tile of q: 4 lanes cover one s-row (64 B contiguous,
  // line-aligned), 256 threads cover 64 s-rows per pass, 8 passes.
  {
    const int lane4 = t & 3;
    const int srow  = t >> 2;        // 0..63
    const int cvec  = lane4 * 4;
#pragma unroll
    for (int k = 0; k < 8; ++k) {
      const int ss = srow + k * 64;
      const float4 v = *reinterpret_cast<const float4*>(
          &q[((size_t)b * kS + (size_t)(s0 + ss)) * kD + (c0 + cvec)]);
      tile[cvec + 0][ss] = v.x;   // 2-way LDS bank aliasing: free
      tile[cvec + 1][ss] = v.y;
      tile[cvec + 2][ss] = v.z;
      tile[cvec + 3][ss] = v.w;
    }
  }
  __syncthreads();

  // Write phase: 256 threads x float4 = 1024 floats = 2 full rows of 512 per
  // pass. Each wave writes 1 KB contiguous; a row pair = 2x 2 KB fragments.
  const int half = t >> 7;           // which row of the pair
  const int soff = (t & 127) * 4;    // 0..508
  for (int nn = 0; nn < NPB; ++nn) {
    const int n = n0 + nn;
    const size_t base_bn = ((size_t)(b * kN + n)) * kD;
#pragma unroll
    for (int rg = 0; rg < TC / 2; ++rg) {
      const int r = rg * 2 + half;
      const float sc = ws[nn][r];    // wave-uniform -> LDS broadcast
      const float4 v = *reinterpret_cast<const float4*>(&tile[r][soff]);
      v4f o;
      o.x = v.x * sc;
      o.y = v.y * sc;
      o.z = v.z * sc;
      o.w = v.w * sc;
      __builtin_nontemporal_store(o, reinterpret_cast<v4f*>(
          &out[(base_bn + (size_t)(c0 + r)) * kS + (size_t)(s0 + soff)]));
    }
  }
}

extern "C" void kernel_launch(void* const* d_in, const int* in_sizes, int n_in,
                              void* d_out, int out_size, void* d_ws, size_t ws_size,
                              hipStream_t stream) {
  const float* q = (const float*)d_in[0];  // (B, S, D)
  const float* w = (const float*)d_in[1];  // (N, D)
  float* out = (float*)d_out;              // (B*N, D, S)

  dim3 grid(kS / TS, kD / TC, kB * NSPLIT);  // 4 x 16 x 16 = 1024 blocks
  frw_kernel<<<grid, 256, 0, stream>>>(q, w, out);
}